// Round 12
// baseline (326.472 us; speedup 1.0000x reference)
//
#include <hip/hip_runtime.h>
#include <hip/hip_bf16.h>
#include <math.h>

// Problem constants
#define B    2
#define CIN  64
#define LIN  8192
#define L    2048
#define D    128
#define DI   256
#define NS   16
#define RK   8
#define NSTREAM 4        // (dir, batch): s = dir*2 + b
#define CH   32          // tokens per chunk/block
#define NCH  (L/CH)      // 64 chunks per stream
#define TOK  (NSTREAM*L) // 8192
#define SZ_D ((size_t)TOK*D)     // 1,048,576 floats
#define SZ_DI ((size_t)TOK*DI)   // 2,097,152 elems
// LDS row strides (ushorts)
#define SXM 280
#define SHN 152

typedef short  bfrag __attribute__((ext_vector_type(8)));
typedef float  facc  __attribute__((ext_vector_type(4)));
#define MFMA __builtin_amdgcn_mfma_f32_16x16x32_bf16

__device__ __forceinline__ float sigmoidf_(float x){ return 1.f/(1.f+__expf(-x)); }
__device__ __forceinline__ float siluf_(float x){ return x*sigmoidf_(x); }
__device__ __forceinline__ ushort f2bf(float f){
    unsigned u = __float_as_uint(f);
    u += 0x7fffu + ((u>>16)&1u);
    return (ushort)(u>>16);
}
__device__ __forceinline__ float bf2f(ushort u){ return __uint_as_float(((unsigned)u)<<16); }
__device__ __forceinline__ float softplusf_(float t){
    return (t > 20.f) ? t : __logf(1.f + __expf(t));
}

// ---------------- weight conversion
// dst: wbd(32768) | wbi(393216) | wbo(196608) | wbx(98304, 40->64 pad)
__global__ void k_cvtall(const float* __restrict__ cw, const float* __restrict__ ipw,
                         const float* __restrict__ opw, const float* __restrict__ xpw,
                         ushort* __restrict__ dst){
    int i = blockIdx.x*256 + threadIdx.x;
    ushort v;
    if (i < 32768)       v = f2bf(cw[i]);
    else if (i < 425984) v = f2bf(ipw[i-32768]);
    else if (i < 622592) v = f2bf(opw[i-425984]);
    else {
        int t = i - 622592;
        int k = t & 255, nr = (t>>8) & 63, j = t>>14;
        v = (nr < 40) ? f2bf(xpw[((size_t)j*40 + nr)*256 + k]) : (ushort)0;
    }
    dst[i] = v;
}

// ---------------- fused patch-pack + downsample GEMM + bias + silu, dual write
__global__ void k_down(const float* __restrict__ x, const ushort* __restrict__ wd,
                       const float* __restrict__ bias, float* __restrict__ h){
    __shared__ ushort sxd[64*SXM];
    int tid = threadIdx.x;
    int m0 = blockIdx.x*64;
    int b = m0 >> 11;
    int l0 = m0 & 2047;
    for (int idx = tid; idx < 64*64; idx += 256){
        int t = idx & 63, cc = idx >> 6;     // coalesced: consecutive t per wave
        float4 v = *(const float4*)(x + ((size_t)(b*CIN + cc))*LIN + 4*(l0+t));
        ushort4 o; o.x=f2bf(v.x); o.y=f2bf(v.y); o.z=f2bf(v.z); o.w=f2bf(v.w);
        *(ushort4*)&sxd[t*SXM + cc*4] = o;
    }
    __syncthreads();
    int w = tid>>6, lane = tid&63, rw = w>>1, cw = w&1;
    int q = lane>>4, r = lane&15;
    int n0 = blockIdx.y*64 + cw*32;
    const ushort* b0p = wd + (size_t)(n0 + r)*256 + q*8;
    const ushort* b1p = b0p + (size_t)16*256;
    facc acc[2][2] = {};
    #pragma unroll
    for (int kb=0; kb<8; ++kb){
        bfrag a0 = *(bfrag*)&sxd[(rw*32 + r)*SXM + kb*32 + q*8];
        bfrag a1 = *(bfrag*)&sxd[(rw*32 + 16 + r)*SXM + kb*32 + q*8];
        bfrag b0 = *(const bfrag*)(b0p + kb*32);
        bfrag b1 = *(const bfrag*)(b1p + kb*32);
        acc[0][0] = MFMA(a0,b0,acc[0][0],0,0,0);
        acc[0][1] = MFMA(a0,b1,acc[0][1],0,0,0);
        acc[1][0] = MFMA(a1,b0,acc[1][0],0,0,0);
        acc[1][1] = MFMA(a1,b1,acc[1][1],0,0,0);
    }
    #pragma unroll
    for (int im=0; im<2; ++im)
    #pragma unroll
    for (int in=0; in<2; ++in){
        int col = n0 + in*16 + r;
        float bv = bias[col];
        #pragma unroll
        for (int r2=0; r2<4; ++r2){
            int row = m0 + rw*32 + im*16 + q*4 + r2;
            int bb = row >> 11, l = row & 2047;
            float v = siluf_(acc[im][in][r2] + bv);
            h[((size_t)(bb*L + l))*D + col] = v;
            h[((size_t)((2+bb)*L + (L-1-l)))*D + col] = v;
        }
    }
}

// ---------------- k_head: resln + in_proj + conv + x_proj + scan1, per 32-token chunk
// summary layout: [chunk][d*16 + n]  (tail folds with float4 loads)
__global__ void __launch_bounds__(256,2)
k_head(const float* __restrict__ curIn, const float* __restrict__ resIn,
       float* __restrict__ resOut,
       const float* __restrict__ lnw, const float* __restrict__ lnb,
       const ushort* __restrict__ wbi, const ushort* __restrict__ wbx,
       const float* __restrict__ cw, const float* __restrict__ cb,
       const float* __restrict__ Wdt, const float* __restrict__ bdt,
       const float* __restrict__ A_log,
       ushort* __restrict__ zb, ushort* __restrict__ xcb,
       float* __restrict__ dtr, float* __restrict__ Bc, float* __restrict__ Cc,
       float* __restrict__ Aprod, float* __restrict__ Bend, int blk, int first){
    __shared__ ushort smHn[35*SHN];   // LN out: rows 0..31 owned, 32..34 halo (-3,-2,-1)
    __shared__ ushort smXm[35*SXM];   // xm bf16 (rows 32..34 = halo); conv overwrites in place
    __shared__ float  smDbc[32*68];   // xproj out
    const int tid = threadIdx.x;
    const int bi = blockIdx.x;
    const int s = bi >> 6, c = bi & 63;
    const int j = (s>>1)*3 + blk;
    const int base_tok = s*L + c*CH;

    // ---- residual + LN (owned 32 tokens; 8 lanes per token) ----
    {
        int t = tid >> 3, g8 = tid & 7;
        size_t off = (size_t)(base_tok + t)*D + g8*16;
        float4 v[4];
        const float4* cp = (const float4*)(curIn + off);
        #pragma unroll
        for (int i=0;i<4;++i) v[i] = cp[i];
        if (!first){
            const float4* rp = (const float4*)(resIn + off);
            #pragma unroll
            for (int i=0;i<4;++i){ float4 rv=rp[i]; v[i].x+=rv.x; v[i].y+=rv.y; v[i].z+=rv.z; v[i].w+=rv.w; }
        }
        {
            float4* ro = (float4*)(resOut + off);
            #pragma unroll
            for (int i=0;i<4;++i) ro[i] = v[i];
        }
        float s1=0.f, s2=0.f;
        #pragma unroll
        for (int i=0;i<4;++i){
            s1 += v[i].x+v[i].y+v[i].z+v[i].w;
            s2 += v[i].x*v[i].x+v[i].y*v[i].y+v[i].z*v[i].z+v[i].w*v[i].w;
        }
        s1 += __shfl_xor(s1,1); s2 += __shfl_xor(s2,1);
        s1 += __shfl_xor(s1,2); s2 += __shfl_xor(s2,2);
        s1 += __shfl_xor(s1,4); s2 += __shfl_xor(s2,4);
        float mean = s1*(1.f/128.f);
        float var  = s2*(1.f/128.f) - mean*mean;
        float rstd = rsqrtf(var + 1e-5f);
        const float4* lwp = (const float4*)(lnw + j*D + g8*16);
        const float4* lbp = (const float4*)(lnb + j*D + g8*16);
        #pragma unroll
        for (int i=0;i<4;++i){
            float4 lw = lwp[i], lb = lbp[i];
            ushort4 o;
            o.x = f2bf((v[i].x-mean)*rstd*lw.x + lb.x);
            o.y = f2bf((v[i].y-mean)*rstd*lw.y + lb.y);
            o.z = f2bf((v[i].z-mean)*rstd*lw.z + lb.z);
            o.w = f2bf((v[i].w-mean)*rstd*lw.w + lb.w);
            *(ushort4*)&smHn[t*SHN + g8*16 + i*4] = o;
        }
    }
    // ---- halo LN (3 tokens, threads 0..23; no res write) ----
    if (c > 0 && tid < 24){
        int t = tid >> 3, g8 = tid & 7;
        size_t off = (size_t)(base_tok - 3 + t)*D + g8*16;
        float4 v[4];
        const float4* cp = (const float4*)(curIn + off);
        #pragma unroll
        for (int i=0;i<4;++i) v[i] = cp[i];
        if (!first){
            const float4* rp = (const float4*)(resIn + off);
            #pragma unroll
            for (int i=0;i<4;++i){ float4 rv=rp[i]; v[i].x+=rv.x; v[i].y+=rv.y; v[i].z+=rv.z; v[i].w+=rv.w; }
        }
        float s1=0.f, s2=0.f;
        #pragma unroll
        for (int i=0;i<4;++i){
            s1 += v[i].x+v[i].y+v[i].z+v[i].w;
            s2 += v[i].x*v[i].x+v[i].y*v[i].y+v[i].z*v[i].z+v[i].w*v[i].w;
        }
        s1 += __shfl_xor(s1,1); s2 += __shfl_xor(s2,1);
        s1 += __shfl_xor(s1,2); s2 += __shfl_xor(s2,2);
        s1 += __shfl_xor(s1,4); s2 += __shfl_xor(s2,4);
        float mean = s1*(1.f/128.f);
        float var  = s2*(1.f/128.f) - mean*mean;
        float rstd = rsqrtf(var + 1e-5f);
        const float4* lwp = (const float4*)(lnw + j*D + g8*16);
        const float4* lbp = (const float4*)(lnb + j*D + g8*16);
        #pragma unroll
        for (int i=0;i<4;++i){
            float4 lw = lwp[i], lb = lbp[i];
            ushort4 o;
            o.x = f2bf((v[i].x-mean)*rstd*lw.x + lb.x);
            o.y = f2bf((v[i].y-mean)*rstd*lw.y + lb.y);
            o.z = f2bf((v[i].z-mean)*rstd*lw.z + lb.z);
            o.w = f2bf((v[i].w-mean)*rstd*lw.w + lb.w);
            *(ushort4*)&smHn[(32+t)*SHN + g8*16 + i*4] = o;
        }
    }
    __syncthreads();

    // ---- in_proj GEMM: M=48 (3rd tile = halo, rows 32..34 valid), N=512, K=128 ----
    {
        int w = tid>>6, lane = tid&63, q = lane>>4, r = lane&15;
        bfrag a[3][4];
        #pragma unroll
        for (int rt=0; rt<3; ++rt)
        #pragma unroll
        for (int kb=0; kb<4; ++kb)
            a[rt][kb] = *(bfrag*)&smHn[(rt*16 + r)*SHN + kb*32 + q*8];
        #pragma unroll
        for (int ct=0; ct<8; ++ct){
            int n0 = w*128 + ct*16;
            const ushort* bp = wbi + ((size_t)j*512 + n0 + r)*128 + q*8;
            facc a0 = {}, a1 = {}, a2 = {};
            #pragma unroll
            for (int kb=0; kb<4; ++kb){
                bfrag bv = *(const bfrag*)(bp + kb*32);
                a0 = MFMA(a[0][kb], bv, a0, 0,0,0);
                a1 = MFMA(a[1][kb], bv, a1, 0,0,0);
                a2 = MFMA(a[2][kb], bv, a2, 0,0,0);
            }
            int colL = n0 + r;
            if (colL < DI){
                #pragma unroll
                for (int r2=0;r2<4;++r2){
                    int rr = q*4 + r2;
                    smXm[rr*SXM + colL]      = f2bf(a0[r2]);
                    smXm[(16+rr)*SXM + colL] = f2bf(a1[r2]);
                    if (rr < 3) smXm[(32+rr)*SXM + colL] = f2bf(a2[r2]);
                }
            } else {
                int cz = colL - DI;
                #pragma unroll
                for (int r2=0;r2<4;++r2){
                    int rr = q*4 + r2;
                    zb[(size_t)(base_tok + rr)*DI + cz]      = f2bf(a0[r2]);
                    zb[(size_t)(base_tok + 16 + rr)*DI + cz] = f2bf(a1[r2]);
                }
            }
        }
    }
    __syncthreads();

    // ---- conv + silu (thread-per-d); overwrite smXm[i] in place after reading it ----
    {
        const float* w4 = cw + ((size_t)j*DI + tid)*4;
        float cw0=w4[0], cw1=w4[1], cw2=w4[2], cw3=w4[3];
        float cbb = cb[j*DI + tid];
        float xm1=0.f, xm2=0.f, xm3=0.f;
        if (c > 0){
            xm3 = bf2f(smXm[32*SXM + tid]);
            xm2 = bf2f(smXm[33*SXM + tid]);
            xm1 = bf2f(smXm[34*SXM + tid]);
        }
        #pragma unroll 4
        for (int i=0;i<CH;++i){
            float x0 = bf2f(smXm[i*SXM + tid]);
            float v = siluf_(cbb + cw3*x0 + cw2*xm1 + cw1*xm2 + cw0*xm3);
            ushort us = f2bf(v);
            smXm[i*SXM + tid] = us;               // safe: same thread read this cell
            xcb[(size_t)(base_tok+i)*DI + tid] = us;
            xm3 = xm2; xm2 = xm1; xm1 = x0;
        }
    }
    __syncthreads();

    // ---- x_proj GEMM: M=32, N=64(pad40), K=256 (A = conv out, now in smXm) ----
    {
        int w = tid>>6, lane = tid&63, q = lane>>4, r = lane&15;
        facc a0 = {}, a1 = {};
        const ushort* bp = wbx + ((size_t)j*64 + w*16 + r)*256 + q*8;
        #pragma unroll
        for (int kb=0; kb<8; ++kb){
            bfrag av0 = *(bfrag*)&smXm[r*SXM + kb*32 + q*8];
            bfrag av1 = *(bfrag*)&smXm[(16+r)*SXM + kb*32 + q*8];
            bfrag bv  = *(const bfrag*)(bp + kb*32);
            a0 = MFMA(av0, bv, a0, 0,0,0);
            a1 = MFMA(av1, bv, a1, 0,0,0);
        }
        int col = w*16 + r;
        #pragma unroll
        for (int r2=0;r2<4;++r2){
            int rr = q*4 + r2;
            smDbc[rr*68 + col]      = a0[r2];
            smDbc[(16+rr)*68 + col] = a1[r2];
            int row0 = base_tok + rr, row1 = base_tok + 16 + rr;
            if      (col < 8){  dtr[(size_t)row0*RK + col] = a0[r2];      dtr[(size_t)row1*RK + col] = a1[r2]; }
            else if (col < 24){ Bc [(size_t)row0*NS + (col-8)] = a0[r2];  Bc [(size_t)row1*NS + (col-8)] = a1[r2]; }
            else if (col < 40){ Cc [(size_t)row0*NS + (col-24)] = a0[r2]; Cc [(size_t)row1*NS + (col-24)] = a1[r2]; }
        }
    }
    __syncthreads();

    // ---- scan1: local chunk summary (thread-per-d); write [d*16+n] layout ----
    {
        float A[NS], wv[RK];
        const float* ar = A_log + ((size_t)j*DI + tid)*NS;
        #pragma unroll
        for (int n=0;n<NS;++n) A[n] = -__expf(ar[n]);
        const float* wr = Wdt + ((size_t)j*DI + tid)*RK;
        #pragma unroll
        for (int r=0;r<RK;++r) wv[r] = wr[r];
        float bb2 = bdt[j*DI + tid];
        float ap[NS], hs[NS];
        #pragma unroll
        for (int n=0;n<NS;++n){ ap[n]=1.f; hs[n]=0.f; }
        #pragma unroll 4
        for (int l=0;l<CH;++l){
            float t = bb2;
            #pragma unroll
            for (int r=0;r<RK;++r) t += smDbc[l*68+r]*wv[r];
            float dtv = softplusf_(t);
            float xv  = bf2f(smXm[l*SXM + tid]);
            float dbx = dtv*xv;
            #pragma unroll
            for (int n=0;n<NS;++n){
                float dA = __expf(dtv*A[n]);
                ap[n] *= dA;
                hs[n] = dA*hs[n] + dbx*smDbc[l*68+8+n];
            }
        }
        float4* Ap4 = (float4*)(Aprod + (size_t)bi*4096 + tid*16);
        float4* Bp4 = (float4*)(Bend  + (size_t)bi*4096 + tid*16);
        #pragma unroll
        for (int nq=0;nq<4;++nq){
            Ap4[nq] = *(float4*)&ap[nq*4];
            Bp4[nq] = *(float4*)&hs[nq*4];
        }
    }
}

// ---------------- k_tail: fold predecessors + scan2 + gate + out_proj (CH=32)
__global__ void k_tail(const float* __restrict__ dtr, const ushort* __restrict__ xcb,
                       const float* __restrict__ Bc, const float* __restrict__ Cc,
                       const float* __restrict__ A_log,
                       const float* __restrict__ Wdt, const float* __restrict__ bdt,
                       const float* __restrict__ Aprod, const float* __restrict__ Bend,
                       const ushort* __restrict__ zb,
                       const float* __restrict__ Dp, const ushort* __restrict__ wbo,
                       float* __restrict__ cur, int blk){
    int c = blockIdx.x, s = blockIdx.y; int j = (s>>1)*3 + blk;
    int d = threadIdx.x;
    __shared__ float sB[CH*NS], sC[CH*NS], sdtr[CH*RK];
    __shared__ ushort sg[CH*SXM];
    int base_tok = s*L + c*CH;
    sB[d]     = Bc[(size_t)base_tok*NS + d];
    sB[256+d] = Bc[(size_t)base_tok*NS + 256 + d];
    sC[d]     = Cc[(size_t)base_tok*NS + d];
    sC[256+d] = Cc[(size_t)base_tok*NS + 256 + d];
    sdtr[d]   = dtr[(size_t)base_tok*RK + d];
    float A[NS], wv[RK];
    const float* ar = A_log + ((size_t)j*DI + d)*NS;
    #pragma unroll
    for (int n=0;n<NS;++n) A[n] = -__expf(ar[n]);
    const float* wr = Wdt + ((size_t)j*DI + d)*RK;
    #pragma unroll
    for (int r=0;r<RK;++r) wv[r] = wr[r];
    float bb = bdt[j*DI + d];
    float Dpd = Dp[j*DI + d];

    // ---- fold predecessors' summaries: h = A_k*h + B_k, k = 0..c-1 (2-stage pipeline)
    float hs[NS];
    #pragma unroll
    for (int n=0;n<NS;++n) hs[n] = 0.f;
    {
        size_t sbase = (size_t)(s*NCH)*4096 + d*16;
        float4 a4[4], b4[4], a4n[4], b4n[4];
        if (c > 0){
            const float4* A4 = (const float4*)(Aprod + sbase);
            const float4* B4 = (const float4*)(Bend  + sbase);
            #pragma unroll
            for (int nq=0;nq<4;++nq){ a4[nq]=A4[nq]; b4[nq]=B4[nq]; }
        }
        for (int k=0; k<c; ++k){
            if (k+1 < c){
                const float4* A4 = (const float4*)(Aprod + sbase + (size_t)(k+1)*4096);
                const float4* B4 = (const float4*)(Bend  + sbase + (size_t)(k+1)*4096);
                #pragma unroll
                for (int nq=0;nq<4;++nq){ a4n[nq]=A4[nq]; b4n[nq]=B4[nq]; }
            }
            #pragma unroll
            for (int nq=0;nq<4;++nq){
                float4 h4 = *(float4*)&hs[nq*4];
                h4.x = a4[nq].x*h4.x + b4[nq].x;
                h4.y = a4[nq].y*h4.y + b4[nq].y;
                h4.z = a4[nq].z*h4.z + b4[nq].z;
                h4.w = a4[nq].w*h4.w + b4[nq].w;
                *(float4*)&hs[nq*4] = h4;
            }
            #pragma unroll
            for (int nq=0;nq<4;++nq){ a4[nq]=a4n[nq]; b4[nq]=b4n[nq]; }
        }
    }
    __syncthreads();
    #pragma unroll 4
    for (int l=0;l<CH;++l){
        float t = bb;
        #pragma unroll
        for (int r=0;r<RK;++r) t += sdtr[l*RK+r]*wv[r];
        float dtv = softplusf_(t);
        float xv  = bf2f(xcb[(size_t)(base_tok+l)*DI + d]);
        float dbx = dtv*xv;
        float p = 0.f;
        #pragma unroll
        for (int n=0;n<NS;++n){
            float dA = __expf(dtv*A[n]);
            hs[n] = dA*hs[n] + dbx*sB[l*NS+n];
            p += hs[n]*sC[l*NS+n];
        }
        float zv = bf2f(zb[(size_t)(base_tok+l)*DI + d]);
        sg[l*SXM + d] = f2bf((p + Dpd*xv)*siluf_(zv));
    }
    __syncthreads();
    // out_proj: M=32 (2 rt), N=128; wave w -> cols [w*32, w*32+32)
    int w = d>>6, lane = d&63, q = lane>>4, r = lane&15;
    facc acc[2][2] = {};
    const ushort* b0p = wbo + ((size_t)j*128 + w*32 + r)*256 + q*8;
    const ushort* b1p = b0p + 16*256;
    #pragma unroll
    for (int kb=0; kb<8; ++kb){
        bfrag av0 = *(bfrag*)&sg[r*SXM + kb*32 + q*8];
        bfrag av1 = *(bfrag*)&sg[(16+r)*SXM + kb*32 + q*8];
        bfrag bv0 = *(const bfrag*)(b0p + kb*32);
        bfrag bv1 = *(const bfrag*)(b1p + kb*32);
        acc[0][0] = MFMA(av0,bv0,acc[0][0],0,0,0);
        acc[0][1] = MFMA(av0,bv1,acc[0][1],0,0,0);
        acc[1][0] = MFMA(av1,bv0,acc[1][0],0,0,0);
        acc[1][1] = MFMA(av1,bv1,acc[1][1],0,0,0);
    }
    #pragma unroll
    for (int rt=0; rt<2; ++rt)
    #pragma unroll
    for (int ct=0; ct<2; ++ct){
        int col = w*32 + ct*16 + r;
        #pragma unroll
        for (int r2=0;r2<4;++r2){
            int row = base_tok + rt*16 + q*4 + r2;
            cur[(size_t)row*D + col] = acc[rt][ct][r2];
        }
    }
}

// ---------------- final combine: out0 via LDS transpose (res already in out's rf/rb region)
__global__ void k_final(const float* __restrict__ cur, const float* __restrict__ res,
                        float* __restrict__ out){
    __shared__ float tile[128*33];
    int tid = threadIdx.x;
    int c = blockIdx.x, b = blockIdx.y;
    int t = tid>>3, g8 = tid&7;
    int lf = c*32 + t, lb = L-1-lf;
    size_t fo = ((size_t)(b*L + lf))*D + g8*16;
    size_t bo = ((size_t)((2+b)*L + lb))*D + g8*16;
    #pragma unroll
    for (int i=0;i<4;++i){
        float4 cf  = *(const float4*)(cur + fo + i*4);
        float4 rf  = *(const float4*)(res + fo + i*4);
        float4 cb2 = *(const float4*)(cur + bo + i*4);
        float4 rb2 = *(const float4*)(res + bo + i*4);
        int db = g8*16 + i*4;
        tile[(db+0)*33 + t] = cf.x+rf.x+cb2.x+rb2.x;
        tile[(db+1)*33 + t] = cf.y+rf.y+cb2.y+rb2.y;
        tile[(db+2)*33 + t] = cf.z+rf.z+cb2.z+rb2.z;
        tile[(db+3)*33 + t] = cf.w+rf.w+cb2.w+rb2.w;
    }
    __syncthreads();
    int d = tid>>1, hf = tid&1;
    size_t obase = ((size_t)(b*D + d))*L + c*32 + hf*16;
    #pragma unroll
    for (int i=0;i<4;++i){
        float4 o4;
        o4.x = tile[d*33 + hf*16 + i*4 + 0];
        o4.y = tile[d*33 + hf*16 + i*4 + 1];
        o4.z = tile[d*33 + hf*16 + i*4 + 2];
        o4.w = tile[d*33 + hf*16 + i*4 + 3];
        *(float4*)(out + obase + i*4) = o4;
    }
}

extern "C" void kernel_launch(void* const* d_in, const int* in_sizes, int n_in,
                              void* d_out, int out_size, void* d_ws, size_t ws_size,
                              hipStream_t stream){
    const float* x         = (const float*)d_in[0];
    const float* convd_w   = (const float*)d_in[1];
    const float* convd_b   = (const float*)d_in[2];
    const float* ln_w      = (const float*)d_in[3];
    const float* ln_b      = (const float*)d_in[4];
    const float* in_proj_w = (const float*)d_in[5];
    const float* conv_w    = (const float*)d_in[6];
    const float* conv_b    = (const float*)d_in[7];
    const float* xproj_w   = (const float*)d_in[8];
    const float* dtproj_w  = (const float*)d_in[9];
    const float* dtproj_b  = (const float*)d_in[10];
    const float* A_log     = (const float*)d_in[11];
    const float* Dparam    = (const float*)d_in[12];
    const float* outproj_w = (const float*)d_in[13];

    // res0 lives directly in d_out's rf/rb region (layout matches exactly)
    float* res0 = (float*)d_out + (size_t)2*D*L;

    float* ws = (float*)d_ws;
    float* h     = ws; ws += SZ_D;
    float* res1  = ws; ws += SZ_D;
    float* cur   = ws; ws += SZ_D;
    float* Aprod = ws; ws += SZ_D;   // NSTREAM*NCH*NS*DI = SZ_D, layout [chunk][d*16+n]
    float* Bend  = ws; ws += SZ_D;
    float* dtr   = ws; ws += (size_t)TOK*RK;
    float* Bc    = ws; ws += (size_t)TOK*NS;
    float* Cc    = ws; ws += (size_t)TOK*NS;
    ushort* zb   = (ushort*)ws; ws += SZ_DI/2;   // bf16
    ushort* xcb  = (ushort*)ws; ws += SZ_DI/2;   // bf16
    ushort* wall = (ushort*)ws;
    ushort* wbd  = wall;
    ushort* wbi  = wall + 32768;
    ushort* wbo  = wall + 425984;
    ushort* wbx  = wall + 622592;

    k_cvtall<<<2816, 256, 0, stream>>>(convd_w, in_proj_w, outproj_w, xproj_w, wall);
    k_down<<<dim3(64, 2), 256, 0, stream>>>(x, wbd, convd_b, h);

    // res ping-pong: blk0 -> res0, blk1 -> res1, blk2 -> res0 (final reads res0 = out region)
    float* resin[3]  = { nullptr, res0, res1 };
    float* resout[3] = { res0,    res1, res0 };
    for (int blk = 0; blk < 3; ++blk){
        const float* ci = (blk==0) ? h : cur;
        const float* ri = (blk==0) ? h : resin[blk];
        k_head<<<NSTREAM*NCH, 256, 0, stream>>>(ci, ri, resout[blk], ln_w, ln_b, wbi, wbx,
                                                conv_w, conv_b, dtproj_w, dtproj_b, A_log,
                                                zb, xcb, dtr, Bc, Cc, Aprod, Bend, blk, blk==0);
        k_tail<<<dim3(NCH, NSTREAM), 256, 0, stream>>>(dtr, xcb, Bc, Cc, A_log,
                                                       dtproj_w, dtproj_b, Aprod, Bend, zb,
                                                       Dparam, wbo, cur, blk);
    }

    k_final<<<dim3(NCH, B), 256, 0, stream>>>(cur, res0, (float*)d_out);
}

// Round 13
// 254.866 us; speedup vs baseline: 1.2810x; 1.2810x over previous
//
#include <hip/hip_runtime.h>
#include <hip/hip_bf16.h>
#include <math.h>

// Problem constants
#define B    2
#define CIN  64
#define LIN  8192
#define L    2048
#define D    128
#define DI   256
#define NS   16
#define RK   8
#define NSTREAM 4        // (dir, batch): s = dir*2 + b
#define CH   32          // tokens per chunk/block
#define NCH  (L/CH)      // 64 chunks per stream
#define TOK  (NSTREAM*L) // 8192
#define SZ_D ((size_t)TOK*D)     // 1,048,576 floats
#define SZ_DI ((size_t)TOK*DI)   // 2,097,152 elems
// LDS row strides (ushorts)
#define SXM 280
#define SHN 152

typedef short  bfrag __attribute__((ext_vector_type(8)));
typedef float  facc  __attribute__((ext_vector_type(4)));
#define MFMA __builtin_amdgcn_mfma_f32_16x16x32_bf16

__device__ __forceinline__ float sigmoidf_(float x){ return 1.f/(1.f+__expf(-x)); }
__device__ __forceinline__ float siluf_(float x){ return x*sigmoidf_(x); }
__device__ __forceinline__ ushort f2bf(float f){
    unsigned u = __float_as_uint(f);
    u += 0x7fffu + ((u>>16)&1u);
    return (ushort)(u>>16);
}
__device__ __forceinline__ float bf2f(ushort u){ return __uint_as_float(((unsigned)u)<<16); }
__device__ __forceinline__ float softplusf_(float t){
    return (t > 20.f) ? t : __logf(1.f + __expf(t));
}

// ---------------- weight conversion
// dst: wbd(32768) | wbi(393216) | wbo(196608) | wbx(98304, 40->64 pad)
__global__ void k_cvtall(const float* __restrict__ cw, const float* __restrict__ ipw,
                         const float* __restrict__ opw, const float* __restrict__ xpw,
                         ushort* __restrict__ dst){
    int i = blockIdx.x*256 + threadIdx.x;
    ushort v;
    if (i < 32768)       v = f2bf(cw[i]);
    else if (i < 425984) v = f2bf(ipw[i-32768]);
    else if (i < 622592) v = f2bf(opw[i-425984]);
    else {
        int t = i - 622592;
        int k = t & 255, nr = (t>>8) & 63, j = t>>14;
        v = (nr < 40) ? f2bf(xpw[((size_t)j*40 + nr)*256 + k]) : (ushort)0;
    }
    dst[i] = v;
}

// ---------------- fused patch-pack + downsample GEMM + bias + silu, dual write
__global__ void k_down(const float* __restrict__ x, const ushort* __restrict__ wd,
                       const float* __restrict__ bias, float* __restrict__ h){
    __shared__ ushort sxd[64*SXM];
    int tid = threadIdx.x;
    int m0 = blockIdx.x*64;
    int b = m0 >> 11;
    int l0 = m0 & 2047;
    for (int idx = tid; idx < 64*64; idx += 256){
        int t = idx & 63, cc = idx >> 6;     // coalesced: consecutive t per wave
        float4 v = *(const float4*)(x + ((size_t)(b*CIN + cc))*LIN + 4*(l0+t));
        ushort4 o; o.x=f2bf(v.x); o.y=f2bf(v.y); o.z=f2bf(v.z); o.w=f2bf(v.w);
        *(ushort4*)&sxd[t*SXM + cc*4] = o;
    }
    __syncthreads();
    int w = tid>>6, lane = tid&63, rw = w>>1, cw = w&1;
    int q = lane>>4, r = lane&15;
    int n0 = blockIdx.y*64 + cw*32;
    const ushort* b0p = wd + (size_t)(n0 + r)*256 + q*8;
    const ushort* b1p = b0p + (size_t)16*256;
    facc acc[2][2] = {};
    #pragma unroll
    for (int kb=0; kb<8; ++kb){
        bfrag a0 = *(bfrag*)&sxd[(rw*32 + r)*SXM + kb*32 + q*8];
        bfrag a1 = *(bfrag*)&sxd[(rw*32 + 16 + r)*SXM + kb*32 + q*8];
        bfrag b0 = *(const bfrag*)(b0p + kb*32);
        bfrag b1 = *(const bfrag*)(b1p + kb*32);
        acc[0][0] = MFMA(a0,b0,acc[0][0],0,0,0);
        acc[0][1] = MFMA(a0,b1,acc[0][1],0,0,0);
        acc[1][0] = MFMA(a1,b0,acc[1][0],0,0,0);
        acc[1][1] = MFMA(a1,b1,acc[1][1],0,0,0);
    }
    #pragma unroll
    for (int im=0; im<2; ++im)
    #pragma unroll
    for (int in=0; in<2; ++in){
        int col = n0 + in*16 + r;
        float bv = bias[col];
        #pragma unroll
        for (int r2=0; r2<4; ++r2){
            int row = m0 + rw*32 + im*16 + q*4 + r2;
            int bb = row >> 11, l = row & 2047;
            float v = siluf_(acc[im][in][r2] + bv);
            h[((size_t)(bb*L + l))*D + col] = v;
            h[((size_t)((2+bb)*L + (L-1-l)))*D + col] = v;
        }
    }
}

// ---------------- k_head: resln + in_proj + conv + x_proj + scan1, per 32-token chunk
__global__ void __launch_bounds__(256,2)
k_head(const float* __restrict__ curIn, const float* __restrict__ resIn,
       float* __restrict__ resOut,
       const float* __restrict__ lnw, const float* __restrict__ lnb,
       const ushort* __restrict__ wbi, const ushort* __restrict__ wbx,
       const float* __restrict__ cw, const float* __restrict__ cb,
       const float* __restrict__ Wdt, const float* __restrict__ bdt,
       const float* __restrict__ A_log,
       ushort* __restrict__ zb, ushort* __restrict__ xcb,
       float* __restrict__ dtr, float* __restrict__ Bc, float* __restrict__ Cc,
       float* __restrict__ Aprod, float* __restrict__ Bend, int blk, int first){
    __shared__ ushort smHn[35*SHN];   // LN out: rows 0..31 owned, 32..34 halo (-3,-2,-1)
    __shared__ ushort smXm[35*SXM];   // xm bf16 (rows 32..34 = halo); conv overwrites in place
    __shared__ float  smDbc[32*68];   // xproj out
    const int tid = threadIdx.x;
    const int bi = blockIdx.x;
    const int s = bi >> 6, c = bi & 63;
    const int j = (s>>1)*3 + blk;
    const int base_tok = s*L + c*CH;

    // ---- residual + LN (owned 32 tokens; 8 lanes per token) ----
    {
        int t = tid >> 3, g8 = tid & 7;
        size_t off = (size_t)(base_tok + t)*D + g8*16;
        float4 v[4];
        const float4* cp = (const float4*)(curIn + off);
        #pragma unroll
        for (int i=0;i<4;++i) v[i] = cp[i];
        if (!first){
            const float4* rp = (const float4*)(resIn + off);
            #pragma unroll
            for (int i=0;i<4;++i){ float4 rv=rp[i]; v[i].x+=rv.x; v[i].y+=rv.y; v[i].z+=rv.z; v[i].w+=rv.w; }
        }
        {
            float4* ro = (float4*)(resOut + off);
            #pragma unroll
            for (int i=0;i<4;++i) ro[i] = v[i];
        }
        float s1=0.f, s2=0.f;
        #pragma unroll
        for (int i=0;i<4;++i){
            s1 += v[i].x+v[i].y+v[i].z+v[i].w;
            s2 += v[i].x*v[i].x+v[i].y*v[i].y+v[i].z*v[i].z+v[i].w*v[i].w;
        }
        s1 += __shfl_xor(s1,1); s2 += __shfl_xor(s2,1);
        s1 += __shfl_xor(s1,2); s2 += __shfl_xor(s2,2);
        s1 += __shfl_xor(s1,4); s2 += __shfl_xor(s2,4);
        float mean = s1*(1.f/128.f);
        float var  = s2*(1.f/128.f) - mean*mean;
        float rstd = rsqrtf(var + 1e-5f);
        const float4* lwp = (const float4*)(lnw + j*D + g8*16);
        const float4* lbp = (const float4*)(lnb + j*D + g8*16);
        #pragma unroll
        for (int i=0;i<4;++i){
            float4 lw = lwp[i], lb = lbp[i];
            ushort4 o;
            o.x = f2bf((v[i].x-mean)*rstd*lw.x + lb.x);
            o.y = f2bf((v[i].y-mean)*rstd*lw.y + lb.y);
            o.z = f2bf((v[i].z-mean)*rstd*lw.z + lb.z);
            o.w = f2bf((v[i].w-mean)*rstd*lw.w + lb.w);
            *(ushort4*)&smHn[t*SHN + g8*16 + i*4] = o;
        }
    }
    // ---- halo LN (3 tokens, threads 0..23; no res write) ----
    if (c > 0 && tid < 24){
        int t = tid >> 3, g8 = tid & 7;
        size_t off = (size_t)(base_tok - 3 + t)*D + g8*16;
        float4 v[4];
        const float4* cp = (const float4*)(curIn + off);
        #pragma unroll
        for (int i=0;i<4;++i) v[i] = cp[i];
        if (!first){
            const float4* rp = (const float4*)(resIn + off);
            #pragma unroll
            for (int i=0;i<4;++i){ float4 rv=rp[i]; v[i].x+=rv.x; v[i].y+=rv.y; v[i].z+=rv.z; v[i].w+=rv.w; }
        }
        float s1=0.f, s2=0.f;
        #pragma unroll
        for (int i=0;i<4;++i){
            s1 += v[i].x+v[i].y+v[i].z+v[i].w;
            s2 += v[i].x*v[i].x+v[i].y*v[i].y+v[i].z*v[i].z+v[i].w*v[i].w;
        }
        s1 += __shfl_xor(s1,1); s2 += __shfl_xor(s2,1);
        s1 += __shfl_xor(s1,2); s2 += __shfl_xor(s2,2);
        s1 += __shfl_xor(s1,4); s2 += __shfl_xor(s2,4);
        float mean = s1*(1.f/128.f);
        float var  = s2*(1.f/128.f) - mean*mean;
        float rstd = rsqrtf(var + 1e-5f);
        const float4* lwp = (const float4*)(lnw + j*D + g8*16);
        const float4* lbp = (const float4*)(lnb + j*D + g8*16);
        #pragma unroll
        for (int i=0;i<4;++i){
            float4 lw = lwp[i], lb = lbp[i];
            ushort4 o;
            o.x = f2bf((v[i].x-mean)*rstd*lw.x + lb.x);
            o.y = f2bf((v[i].y-mean)*rstd*lw.y + lb.y);
            o.z = f2bf((v[i].z-mean)*rstd*lw.z + lb.z);
            o.w = f2bf((v[i].w-mean)*rstd*lw.w + lb.w);
            *(ushort4*)&smHn[(32+t)*SHN + g8*16 + i*4] = o;
        }
    }
    __syncthreads();

    // ---- in_proj GEMM: M=48 (3rd tile = halo, rows 32..34 valid), N=512, K=128 ----
    {
        int w = tid>>6, lane = tid&63, q = lane>>4, r = lane&15;
        bfrag a[3][4];
        #pragma unroll
        for (int rt=0; rt<3; ++rt)
        #pragma unroll
        for (int kb=0; kb<4; ++kb)
            a[rt][kb] = *(bfrag*)&smHn[(rt*16 + r)*SHN + kb*32 + q*8];
        #pragma unroll
        for (int ct=0; ct<8; ++ct){
            int n0 = w*128 + ct*16;
            const ushort* bp = wbi + ((size_t)j*512 + n0 + r)*128 + q*8;
            facc a0 = {}, a1 = {}, a2 = {};
            #pragma unroll
            for (int kb=0; kb<4; ++kb){
                bfrag bv = *(const bfrag*)(bp + kb*32);
                a0 = MFMA(a[0][kb], bv, a0, 0,0,0);
                a1 = MFMA(a[1][kb], bv, a1, 0,0,0);
                a2 = MFMA(a[2][kb], bv, a2, 0,0,0);
            }
            int colL = n0 + r;
            if (colL < DI){
                #pragma unroll
                for (int r2=0;r2<4;++r2){
                    int rr = q*4 + r2;
                    smXm[rr*SXM + colL]      = f2bf(a0[r2]);
                    smXm[(16+rr)*SXM + colL] = f2bf(a1[r2]);
                    if (rr < 3) smXm[(32+rr)*SXM + colL] = f2bf(a2[r2]);
                }
            } else {
                int cz = colL - DI;
                #pragma unroll
                for (int r2=0;r2<4;++r2){
                    int rr = q*4 + r2;
                    zb[(size_t)(base_tok + rr)*DI + cz]      = f2bf(a0[r2]);
                    zb[(size_t)(base_tok + 16 + rr)*DI + cz] = f2bf(a1[r2]);
                }
            }
        }
    }
    __syncthreads();

    // ---- conv + silu (thread-per-d); overwrite smXm[i] in place after reading it ----
    {
        const float* w4 = cw + ((size_t)j*DI + tid)*4;
        float cw0=w4[0], cw1=w4[1], cw2=w4[2], cw3=w4[3];
        float cbb = cb[j*DI + tid];
        float xm1=0.f, xm2=0.f, xm3=0.f;
        if (c > 0){
            xm3 = bf2f(smXm[32*SXM + tid]);
            xm2 = bf2f(smXm[33*SXM + tid]);
            xm1 = bf2f(smXm[34*SXM + tid]);
        }
        #pragma unroll 4
        for (int i=0;i<CH;++i){
            float x0 = bf2f(smXm[i*SXM + tid]);
            float v = siluf_(cbb + cw3*x0 + cw2*xm1 + cw1*xm2 + cw0*xm3);
            ushort us = f2bf(v);
            smXm[i*SXM + tid] = us;               // safe: same thread read this cell
            xcb[(size_t)(base_tok+i)*DI + tid] = us;
            xm3 = xm2; xm2 = xm1; xm1 = x0;
        }
    }
    __syncthreads();

    // ---- x_proj GEMM: M=32, N=64(pad40), K=256 (A = conv out, now in smXm) ----
    {
        int w = tid>>6, lane = tid&63, q = lane>>4, r = lane&15;
        facc a0 = {}, a1 = {};
        const ushort* bp = wbx + ((size_t)j*64 + w*16 + r)*256 + q*8;
        #pragma unroll
        for (int kb=0; kb<8; ++kb){
            bfrag av0 = *(bfrag*)&smXm[r*SXM + kb*32 + q*8];
            bfrag av1 = *(bfrag*)&smXm[(16+r)*SXM + kb*32 + q*8];
            bfrag bv  = *(const bfrag*)(bp + kb*32);
            a0 = MFMA(av0, bv, a0, 0,0,0);
            a1 = MFMA(av1, bv, a1, 0,0,0);
        }
        int col = w*16 + r;
        #pragma unroll
        for (int r2=0;r2<4;++r2){
            int rr = q*4 + r2;
            smDbc[rr*68 + col]      = a0[r2];
            smDbc[(16+rr)*68 + col] = a1[r2];
            int row0 = base_tok + rr, row1 = base_tok + 16 + rr;
            if      (col < 8){  dtr[(size_t)row0*RK + col] = a0[r2];      dtr[(size_t)row1*RK + col] = a1[r2]; }
            else if (col < 24){ Bc [(size_t)row0*NS + (col-8)] = a0[r2];  Bc [(size_t)row1*NS + (col-8)] = a1[r2]; }
            else if (col < 40){ Cc [(size_t)row0*NS + (col-24)] = a0[r2]; Cc [(size_t)row1*NS + (col-24)] = a1[r2]; }
        }
    }
    __syncthreads();

    // ---- scan1: local chunk summary (thread-per-d) ----
    {
        float A[NS], wv[RK];
        const float* ar = A_log + ((size_t)j*DI + tid)*NS;
        #pragma unroll
        for (int n=0;n<NS;++n) A[n] = -__expf(ar[n]);
        const float* wr = Wdt + ((size_t)j*DI + tid)*RK;
        #pragma unroll
        for (int r=0;r<RK;++r) wv[r] = wr[r];
        float bb2 = bdt[j*DI + tid];
        float ap[NS], hs[NS];
        #pragma unroll
        for (int n=0;n<NS;++n){ ap[n]=1.f; hs[n]=0.f; }
        #pragma unroll 4
        for (int l=0;l<CH;++l){
            float t = bb2;
            #pragma unroll
            for (int r=0;r<RK;++r) t += smDbc[l*68+r]*wv[r];
            float dtv = softplusf_(t);
            float xv  = bf2f(smXm[l*SXM + tid]);
            float dbx = dtv*xv;
            #pragma unroll
            for (int n=0;n<NS;++n){
                float dA = __expf(dtv*A[n]);
                ap[n] *= dA;
                hs[n] = dA*hs[n] + dbx*smDbc[l*68+8+n];
            }
        }
        size_t pb = (size_t)bi*4096 + tid;
        #pragma unroll
        for (int n=0;n<NS;++n){
            Aprod[pb + (size_t)n*256] = ap[n];
            Bend [pb + (size_t)n*256] = hs[n];
        }
    }
}

// ---------------- scan mid: fold 64 chunk summaries; Bend becomes carry-in
__global__ void k_scanmid(const float* __restrict__ Aprod, float* __restrict__ Bend){
    int tid = blockIdx.x*128 + threadIdx.x;   // 16384 total
    int s = tid >> 12;
    int nd = tid & 4095;
    size_t base = (size_t)s*NCH*4096 + nd;
    float h = 0.f;
    for (int c0=0; c0<NCH; c0+=16){
        float a[16], b[16];
        #pragma unroll
        for (int i=0;i<16;++i){
            a[i] = Aprod[base + (size_t)(c0+i)*4096];
            b[i] = Bend [base + (size_t)(c0+i)*4096];
        }
        #pragma unroll
        for (int i=0;i<16;++i){
            Bend[base + (size_t)(c0+i)*4096] = h;
            h = a[i]*h + b[i];
        }
    }
}

// ---------------- k_tail: scan2 + gate + out_proj (CH=32)
__global__ void k_tail(const float* __restrict__ dtr, const ushort* __restrict__ xcb,
                       const float* __restrict__ Bc, const float* __restrict__ Cc,
                       const float* __restrict__ A_log,
                       const float* __restrict__ Wdt, const float* __restrict__ bdt,
                       const float* __restrict__ h0, const ushort* __restrict__ zb,
                       const float* __restrict__ Dp, const ushort* __restrict__ wbo,
                       float* __restrict__ cur, int blk){
    int c = blockIdx.x, s = blockIdx.y; int j = (s>>1)*3 + blk;
    int d = threadIdx.x;
    __shared__ float sB[CH*NS], sC[CH*NS], sdtr[CH*RK];
    __shared__ ushort sg[CH*SXM];
    int base_tok = s*L + c*CH;
    sB[d]     = Bc[(size_t)base_tok*NS + d];
    sB[256+d] = Bc[(size_t)base_tok*NS + 256 + d];
    sC[d]     = Cc[(size_t)base_tok*NS + d];
    sC[256+d] = Cc[(size_t)base_tok*NS + 256 + d];
    sdtr[d]   = dtr[(size_t)base_tok*RK + d];
    float A[NS], wv[RK];
    const float* ar = A_log + ((size_t)j*DI + d)*NS;
    #pragma unroll
    for (int n=0;n<NS;++n) A[n] = -__expf(ar[n]);
    const float* wr = Wdt + ((size_t)j*DI + d)*RK;
    #pragma unroll
    for (int r=0;r<RK;++r) wv[r] = wr[r];
    float bb = bdt[j*DI + d];
    float Dpd = Dp[j*DI + d];
    float hs[NS];
    size_t pb = (size_t)(s*NCH + c)*4096 + d;
    #pragma unroll
    for (int n=0;n<NS;++n) hs[n] = h0[pb + (size_t)n*256];
    __syncthreads();
    #pragma unroll 4
    for (int l=0;l<CH;++l){
        float t = bb;
        #pragma unroll
        for (int r=0;r<RK;++r) t += sdtr[l*RK+r]*wv[r];
        float dtv = softplusf_(t);
        float xv  = bf2f(xcb[(size_t)(base_tok+l)*DI + d]);
        float dbx = dtv*xv;
        float p = 0.f;
        #pragma unroll
        for (int n=0;n<NS;++n){
            float dA = __expf(dtv*A[n]);
            hs[n] = dA*hs[n] + dbx*sB[l*NS+n];
            p += hs[n]*sC[l*NS+n];
        }
        float zv = bf2f(zb[(size_t)(base_tok+l)*DI + d]);
        sg[l*SXM + d] = f2bf((p + Dpd*xv)*siluf_(zv));
    }
    __syncthreads();
    // out_proj: M=32 (2 rt), N=128; wave w -> cols [w*32, w*32+32)
    int w = d>>6, lane = d&63, q = lane>>4, r = lane&15;
    facc acc[2][2] = {};
    const ushort* b0p = wbo + ((size_t)j*128 + w*32 + r)*256 + q*8;
    const ushort* b1p = b0p + 16*256;
    #pragma unroll
    for (int kb=0; kb<8; ++kb){
        bfrag av0 = *(bfrag*)&sg[r*SXM + kb*32 + q*8];
        bfrag av1 = *(bfrag*)&sg[(16+r)*SXM + kb*32 + q*8];
        bfrag bv0 = *(const bfrag*)(b0p + kb*32);
        bfrag bv1 = *(const bfrag*)(b1p + kb*32);
        acc[0][0] = MFMA(av0,bv0,acc[0][0],0,0,0);
        acc[0][1] = MFMA(av0,bv1,acc[0][1],0,0,0);
        acc[1][0] = MFMA(av1,bv0,acc[1][0],0,0,0);
        acc[1][1] = MFMA(av1,bv1,acc[1][1],0,0,0);
    }
    #pragma unroll
    for (int rt=0; rt<2; ++rt)
    #pragma unroll
    for (int ct=0; ct<2; ++ct){
        int col = w*32 + ct*16 + r;
        #pragma unroll
        for (int r2=0;r2<4;++r2){
            int row = base_tok + rt*16 + q*4 + r2;
            cur[(size_t)row*D + col] = acc[rt][ct][r2];
        }
    }
}

// ---------------- final combine: out0 via LDS transpose (res lives in out's rf/rb region)
__global__ void k_final(const float* __restrict__ cur, const float* __restrict__ res,
                        float* __restrict__ out){
    __shared__ float tile[128*33];
    int tid = threadIdx.x;
    int c = blockIdx.x, b = blockIdx.y;
    int t = tid>>3, g8 = tid&7;
    int lf = c*32 + t, lb = L-1-lf;
    size_t fo = ((size_t)(b*L + lf))*D + g8*16;
    size_t bo = ((size_t)((2+b)*L + lb))*D + g8*16;
    #pragma unroll
    for (int i=0;i<4;++i){
        float4 cf  = *(const float4*)(cur + fo + i*4);
        float4 rf  = *(const float4*)(res + fo + i*4);
        float4 cb2 = *(const float4*)(cur + bo + i*4);
        float4 rb2 = *(const float4*)(res + bo + i*4);
        int db = g8*16 + i*4;
        tile[(db+0)*33 + t] = cf.x+rf.x+cb2.x+rb2.x;
        tile[(db+1)*33 + t] = cf.y+rf.y+cb2.y+rb2.y;
        tile[(db+2)*33 + t] = cf.z+rf.z+cb2.z+rb2.z;
        tile[(db+3)*33 + t] = cf.w+rf.w+cb2.w+rb2.w;
    }
    __syncthreads();
    int d = tid>>1, hf = tid&1;
    size_t obase = ((size_t)(b*D + d))*L + c*32 + hf*16;
    #pragma unroll
    for (int i=0;i<4;++i){
        float4 o4;
        o4.x = tile[d*33 + hf*16 + i*4 + 0];
        o4.y = tile[d*33 + hf*16 + i*4 + 1];
        o4.z = tile[d*33 + hf*16 + i*4 + 2];
        o4.w = tile[d*33 + hf*16 + i*4 + 3];
        *(float4*)(out + obase + i*4) = o4;
    }
}

extern "C" void kernel_launch(void* const* d_in, const int* in_sizes, int n_in,
                              void* d_out, int out_size, void* d_ws, size_t ws_size,
                              hipStream_t stream){
    const float* x         = (const float*)d_in[0];
    const float* convd_w   = (const float*)d_in[1];
    const float* convd_b   = (const float*)d_in[2];
    const float* ln_w      = (const float*)d_in[3];
    const float* ln_b      = (const float*)d_in[4];
    const float* in_proj_w = (const float*)d_in[5];
    const float* conv_w    = (const float*)d_in[6];
    const float* conv_b    = (const float*)d_in[7];
    const float* xproj_w   = (const float*)d_in[8];
    const float* dtproj_w  = (const float*)d_in[9];
    const float* dtproj_b  = (const float*)d_in[10];
    const float* A_log     = (const float*)d_in[11];
    const float* Dparam    = (const float*)d_in[12];
    const float* outproj_w = (const float*)d_in[13];

    // res0 lives directly in d_out's rf/rb region (layout matches exactly:
    // streams 0,1 = rf (b,l,d), streams 2,3 = rb (b,l,d))
    float* res0 = (float*)d_out + (size_t)2*D*L;

    float* ws = (float*)d_ws;
    float* h     = ws; ws += SZ_D;
    float* res1  = ws; ws += SZ_D;
    float* cur   = ws; ws += SZ_D;
    float* Aprod = ws; ws += SZ_D;   // NSTREAM*NCH*NS*DI = SZ_D, layout [chunk][n*256+d]
    float* Bend  = ws; ws += SZ_D;
    float* dtr   = ws; ws += (size_t)TOK*RK;
    float* Bc    = ws; ws += (size_t)TOK*NS;
    float* Cc    = ws; ws += (size_t)TOK*NS;
    ushort* zb   = (ushort*)ws; ws += SZ_DI/2;   // bf16
    ushort* xcb  = (ushort*)ws; ws += SZ_DI/2;   // bf16
    ushort* wall = (ushort*)ws;
    ushort* wbd  = wall;
    ushort* wbi  = wall + 32768;
    ushort* wbo  = wall + 425984;
    ushort* wbx  = wall + 622592;

    k_cvtall<<<2816, 256, 0, stream>>>(convd_w, in_proj_w, outproj_w, xproj_w, wall);
    k_down<<<dim3(64, 2), 256, 0, stream>>>(x, wbd, convd_b, h);

    // res ping-pong: blk0 -> res0, blk1 -> res1, blk2 -> res0 (final reads res0 = out region)
    float* resin[3]  = { nullptr, res0, res1 };
    float* resout[3] = { res0,    res1, res0 };
    for (int blk = 0; blk < 3; ++blk){
        const float* ci = (blk==0) ? h : cur;
        const float* ri = (blk==0) ? h : resin[blk];
        k_head<<<NSTREAM*NCH, 256, 0, stream>>>(ci, ri, resout[blk], ln_w, ln_b, wbi, wbx,
                                                conv_w, conv_b, dtproj_w, dtproj_b, A_log,
                                                zb, xcb, dtr, Bc, Cc, Aprod, Bend, blk, blk==0);
        k_scanmid<<<128, 128, 0, stream>>>(Aprod, Bend);
        k_tail<<<dim3(NCH, NSTREAM), 256, 0, stream>>>(dtr, xcb, Bc, Cc, A_log,
                                                       dtproj_w, dtproj_b, Bend, zb,
                                                       Dparam, wbo, cur, blk);
    }

    k_final<<<dim3(NCH, B), 256, 0, stream>>>(cur, res0, (float*)d_out);
}